// Round 4
// baseline (202.057 us; speedup 1.0000x reference)
//
#include <hip/hip_runtime.h>

// Chamfer distance loss, fused single-pass brute force, fp32 VALU.
// N=65536 vertices (x), M=8192 samples (y), D=3.
// Each (n,m) distance computed ONCE: feeds per-n row argmin (registers+atomic)
// and per-m col min (chain tree + ds_swizzle butterfly + 2-lane atomic).
// q = d2/2 = 0.5||x||^2 + 0.5||y||^2 - x.y computed as 3 fma + 1 add via
// negated-y precompute. Key = (qbits & ~0x1FFF) | m: uint min == (q,m) lexmin.

constexpr int NP = 65536;
constexpr int MP = 8192;
constexpr int T = 8;              // n-points per thread
constexpr int NB = NP / (256 * T);  // 32 n-group blocks
constexpr int CM = 64;            // m-chunks
constexpr int LM = MP / CM;       // 128 m per chunk

__device__ __forceinline__ unsigned umin32(unsigned a, unsigned b) { return a < b ? a : b; }

// ws layout (bytes):
//   [0,       NP*4)        rowkey (uint per n: qbits&~0x1FFF | argmin m)
//   [NP*4,    +MP*4)       colkey (uint per m: qbits&~0x1FFF | m)
//   [+,       +NP*16)      xp (float4: x0,x1,x2, 0.5*||x||^2)
//   [+,       +MP*16)      yp (float4: -y0,-y1,-y2, 0.5*||y||^2)

__global__ __launch_bounds__(256) void k0_init(const float* __restrict__ x,
                                               const float* __restrict__ y,
                                               unsigned* __restrict__ rowkey,
                                               unsigned* __restrict__ colkey,
                                               float4* __restrict__ xp,
                                               float4* __restrict__ yp,
                                               float* __restrict__ out) {
    int i = blockIdx.x * 256 + threadIdx.x;
    if (i < NP) {
        rowkey[i] = 0xFFFFFFFFu;
        float a = x[i * 3 + 0], b = x[i * 3 + 1], c = x[i * 3 + 2];
        xp[i] = make_float4(a, b, c, 0.5f * fmaf(a, a, fmaf(b, b, c * c)));
    }
    if (i < MP) {
        colkey[i] = 0xFFFFFFFFu;
        float a = y[i * 3 + 0], b = y[i * 3 + 1], c = y[i * 3 + 2];
        yp[i] = make_float4(-a, -b, -c, 0.5f * fmaf(a, a, fmaf(b, b, c * c)));
    }
    if (i == 0) out[0] = 0.f;
}

__global__ __launch_bounds__(256, 6) void k12_fused(const float4* __restrict__ xp,
                                                    const float4* __restrict__ yp,
                                                    unsigned* __restrict__ rowkey,
                                                    unsigned* __restrict__ colkey) {
    int t = threadIdx.x;
    int bx = blockIdx.x & (NB - 1);  // n-group
    int by = blockIdx.x / NB;        // m-chunk
    int nbase = bx * (256 * T);

    float x0[T], x1[T], x2[T], xw[T];
    unsigned kmin[T];
#pragma unroll
    for (int k = 0; k < T; ++k) {
        float4 xv = xp[nbase + t + k * 256];
        x0[k] = xv.x; x1[k] = xv.y; x2[k] = xv.z; xw[k] = xv.w;
        kmin[k] = 0xFFFFFFFFu;
    }

    int m0 = by * LM;
#pragma unroll 2
    for (int m = m0; m < m0 + LM; ++m) {
        float4 yv = yp[m];  // wave-uniform address -> scalar load
        unsigned cmin = 0xFFFFFFFFu;
#pragma unroll
        for (int k = 0; k < T; ++k) {
            // q = 0.5*d2 >= 0 (up to rounding; tiny-negative keys lose the min)
            float q = fmaf(x0[k], yv.x, fmaf(x1[k], yv.y, fmaf(x2[k], yv.z, xw[k] + yv.w)));
            unsigned key = (__float_as_uint(q) & 0xFFFFE000u) | (unsigned)m;
            kmin[k] = umin32(kmin[k], key);
            cmin = umin32(cmin, key);
        }
        // butterfly min within each 32-lane half (imm-pattern swizzles, LDS pipe)
        cmin = umin32(cmin, (unsigned)__builtin_amdgcn_ds_swizzle((int)cmin, 0x041F));
        cmin = umin32(cmin, (unsigned)__builtin_amdgcn_ds_swizzle((int)cmin, 0x081F));
        cmin = umin32(cmin, (unsigned)__builtin_amdgcn_ds_swizzle((int)cmin, 0x101F));
        cmin = umin32(cmin, (unsigned)__builtin_amdgcn_ds_swizzle((int)cmin, 0x201F));
        cmin = umin32(cmin, (unsigned)__builtin_amdgcn_ds_swizzle((int)cmin, 0x401F));
        if ((t & 31) == 0) atomicMin(&colkey[m], cmin);
    }
#pragma unroll
    for (int k = 0; k < T; ++k) atomicMin(&rowkey[nbase + t + k * 256], kmin[k]);
}

__global__ __launch_bounds__(256) void k3_reduce(const unsigned* __restrict__ rowkey,
                                                 const unsigned* __restrict__ colkey,
                                                 const float* __restrict__ probs,
                                                 float* __restrict__ out) {
    int i = blockIdx.x * 256 + threadIdx.x;
    float v = 0.f;
    if (i < NP) {
        unsigned k = rowkey[i];
        unsigned idx = k & 0x1FFFu;
        float dmin = 2.f * __uint_as_float(k & 0xFFFFE000u);  // d2 = 2q
        v = probs[idx] * dmin;  // l2 contribution
    } else {
        int m = i - NP;  // m < MP by grid construction
        unsigned k = colkey[m];
        float dmin = 2.f * __uint_as_float(k & 0xFFFFE000u);
        v = probs[m] * dmin;  // l1 contribution
    }
    for (int off = 32; off > 0; off >>= 1) v += __shfl_down(v, off, 64);
    __shared__ float wsum[4];
    int lane = threadIdx.x & 63;
    int w = threadIdx.x >> 6;
    if (lane == 0) wsum[w] = v;
    __syncthreads();
    if (threadIdx.x == 0) {
        atomicAdd(out, wsum[0] + wsum[1] + wsum[2] + wsum[3]);
    }
}

extern "C" void kernel_launch(void* const* d_in, const int* in_sizes, int n_in,
                              void* d_out, int out_size, void* d_ws, size_t ws_size,
                              hipStream_t stream) {
    const float* x = (const float*)d_in[0];      // [N,3]
    const float* y = (const float*)d_in[1];      // [M,3]
    const float* probs = (const float*)d_in[2];  // [M]
    float* out = (float*)d_out;

    char* ws = (char*)d_ws;
    unsigned* rowkey = (unsigned*)ws;
    unsigned* colkey = (unsigned*)(ws + (size_t)NP * 4);
    float4* xp = (float4*)(ws + (size_t)NP * 4 + (size_t)MP * 4);
    float4* yp = (float4*)(ws + (size_t)NP * 4 + (size_t)MP * 4 + (size_t)NP * 16);

    k0_init<<<NP / 256, 256, 0, stream>>>(x, y, rowkey, colkey, xp, yp, out);
    k12_fused<<<NB * CM, 256, 0, stream>>>(xp, yp, rowkey, colkey);
    k3_reduce<<<(NP + MP) / 256, 256, 0, stream>>>(rowkey, colkey, probs, out);
}